// Round 9
// baseline (240.043 us; speedup 1.0000x reference)
//
#include <hip/hip_runtime.h>
#include <hip/hip_bf16.h>

// Problem constants: B=4, S=1024, D=1024, H=16, HD=64
#define SS 1024
#define DD 1024
#define HH 16
#define HDh 64

typedef short bf16x8 __attribute__((ext_vector_type(8)));
typedef float f32x4 __attribute__((ext_vector_type(4)));

__device__ inline unsigned short f2bf(float f) {
    union { __hip_bfloat16 h; unsigned short u; } cv;
    cv.h = __float2bfloat16(f);   // RTNE
    return cv.u;
}
__device__ inline float bf2f(short u) {
    unsigned int x = ((unsigned int)(unsigned short)u) << 16;
    return __uint_as_float(x);
}

#define PIN4(a, b, c, d) asm volatile("" : "+v"(a), "+v"(b), "+v"(c), "+v"(d))

// async global->LDS, 16B per lane; LDS dest = wave-uniform base + lane*16
__device__ inline void gload_lds16(const unsigned short* g, unsigned short* l) {
    __builtin_amdgcn_global_load_lds(
        (const __attribute__((address_space(1))) unsigned int*)g,
        (__attribute__((address_space(3))) unsigned int*)l, 16, 0, 0);
}

// ---------------- prep: fused cvt3 (blocks 0..4095) + wtrans (4096..8191) ----------------
__global__ __launch_bounds__(256) void prep(
    const float* __restrict__ a, const float* __restrict__ b, const float* __restrict__ c,
    unsigned short* __restrict__ oa, unsigned short* __restrict__ ob, unsigned short* __restrict__ oc,
    const float* __restrict__ Wq, const float* __restrict__ Wk,
    const float* __restrict__ Wv, const float* __restrict__ Wo,
    unsigned short* __restrict__ oq, unsigned short* __restrict__ okk,
    unsigned short* __restrict__ ov, unsigned short* __restrict__ oo)
{
    __shared__ float tile[32][33];
    int bid = blockIdx.x;
    if (bid < 4096) {
        size_t i = ((size_t)bid * 256 + threadIdx.x) * 4;
        float4 va = *(const float4*)(a + i);
        float4 vb = *(const float4*)(b + i);
        float4 vc = *(const float4*)(c + i);
        *(ushort4*)(oa + i) = make_ushort4(f2bf(va.x), f2bf(va.y), f2bf(va.z), f2bf(va.w));
        *(ushort4*)(ob + i) = make_ushort4(f2bf(vb.x), f2bf(vb.y), f2bf(vb.z), f2bf(vb.w));
        *(ushort4*)(oc + i) = make_ushort4(f2bf(vc.x), f2bf(vc.y), f2bf(vc.z), f2bf(vc.w));
    } else {
        int idx = bid - 4096;
        int z = idx >> 10;
        const float* W = z == 0 ? Wq : (z == 1 ? Wk : (z == 2 ? Wv : Wo));
        unsigned short* O = z == 0 ? oq : (z == 1 ? okk : (z == 2 ? ov : oo));
        int e0 = (idx & 31) * 32, d0 = ((idx >> 5) & 31) * 32;
        int r = threadIdx.x >> 3, c4 = (threadIdx.x & 7) * 4;
        float4 v = *(const float4*)(W + (size_t)(d0 + r) * DD + e0 + c4);
        tile[r][c4 + 0] = v.x; tile[r][c4 + 1] = v.y; tile[r][c4 + 2] = v.z; tile[r][c4 + 3] = v.w;
        __syncthreads();
        ushort4 u = make_ushort4(f2bf(tile[c4 + 0][r]), f2bf(tile[c4 + 1][r]),
                                 f2bf(tile[c4 + 2][r]), f2bf(tile[c4 + 3][r]));
        *(ushort4*)(O + (size_t)(e0 + r) * DD + d0 + c4) = u;
    }
}

// ---------------- 128x128 bf16 MFMA GEMM core, m97 2-barrier shape, templated BK ----------------
// LDS comes from caller (pool union): As = pool, Bs = pool + 128*BK.
template<int BK>
__device__ inline void gemm128_core(unsigned short* As, unsigned short* Bs,
                                    const unsigned short* __restrict__ A,
                                    const unsigned short* __restrict__ Bt,
                                    const float* __restrict__ bias,
                                    void* __restrict__ out, int mode, float oscale,
                                    int m0, int n0)
{
    int t = threadIdx.x;
    int w = t >> 6, lane = t & 63, quad = lane >> 4, l15 = lane & 15;
    int wm = w >> 1, wn = w & 1;

    f32x4 zero = {0.f, 0.f, 0.f, 0.f};
    f32x4 acc[4][4];
#pragma unroll
    for (int i = 0; i < 4; i++)
#pragma unroll
        for (int j = 0; j < 4; j++) acc[i][j] = zero;

    for (int k0 = 0; k0 < DD; k0 += BK) {
        __syncthreads();
        if constexpr (BK == 32) {
#pragma unroll
            for (int i = 0; i < 4; i++) {
                int chunk = w + i * 4;            // 0..15
                int half = chunk >> 3;            // 0=A, 1=B
                int c = chunk & 7;                // 16-row chunk within matrix
                const unsigned short* g = (half ? Bt : A)
                    + (size_t)((half ? n0 : m0) + c * 16 + (lane >> 2)) * DD + k0 + (lane & 3) * 8;
                unsigned short* l = (half ? Bs : As) + c * 512 + lane * 8;
                gload_lds16(g, l);
            }
        } else {
#pragma unroll
            for (int i = 0; i < 8; i++) {
                int chunk = w + i * 4;            // 0..31
                int half = chunk >> 4;            // 0=A, 1=B
                int sub = chunk & 15;             // 1KB subchunk: (rowchunk, khalf)
                const unsigned short* g = (half ? Bt : A)
                    + (size_t)((half ? n0 : m0) + (sub >> 1) * 16 + (lane >> 2)) * DD
                    + k0 + (sub & 1) * 32 + (lane & 3) * 8;
                unsigned short* l = (half ? Bs : As) + sub * 512 + lane * 8;
                gload_lds16(g, l);
            }
        }
        __syncthreads();
        if constexpr (BK == 32) {
            bf16x8 af[4], bfr[4];
#pragma unroll
            for (int mi = 0; mi < 4; mi++)
                af[mi] = *(const bf16x8*)&As[(wm * 64 + mi * 16 + l15) * 32 + quad * 8];
#pragma unroll
            for (int ni = 0; ni < 4; ni++)
                bfr[ni] = *(const bf16x8*)&Bs[(wn * 64 + ni * 16 + l15) * 32 + quad * 8];
#pragma unroll
            for (int mi = 0; mi < 4; mi++)
#pragma unroll
                for (int ni = 0; ni < 4; ni++)
                    acc[mi][ni] = __builtin_amdgcn_mfma_f32_16x16x32_bf16(af[mi], bfr[ni], acc[mi][ni], 0, 0, 0);
        } else {
#pragma unroll
            for (int kk = 0; kk < 2; kk++) {
                bf16x8 af[4], bfr[4];
#pragma unroll
                for (int mi = 0; mi < 4; mi++)
                    af[mi] = *(const bf16x8*)&As[((wm * 4 + mi) * 2 + kk) * 512 + l15 * 32 + quad * 8];
#pragma unroll
                for (int ni = 0; ni < 4; ni++)
                    bfr[ni] = *(const bf16x8*)&Bs[((wn * 4 + ni) * 2 + kk) * 512 + l15 * 32 + quad * 8];
#pragma unroll
                for (int mi = 0; mi < 4; mi++)
#pragma unroll
                    for (int ni = 0; ni < 4; ni++)
                        acc[mi][ni] = __builtin_amdgcn_mfma_f32_16x16x32_bf16(af[mi], bfr[ni], acc[mi][ni], 0, 0, 0);
            }
        }
    }

#pragma unroll
    for (int mi = 0; mi < 4; mi++)
#pragma unroll
        for (int ni = 0; ni < 4; ni++) {
            int n = n0 + wn * 64 + ni * 16 + l15;
            float bv = bias[n];
#pragma unroll
            for (int r = 0; r < 4; r++) {
                int m = m0 + wm * 64 + mi * 16 + quad * 4 + r;
                float v = (acc[mi][ni][r] + bv) * oscale;
                if (mode == 2) {
                    ((float*)out)[(size_t)m * DD + n] = v;
                } else {
                    int bb = m >> 10, s = m & 1023, hh = n >> 6, d = n & 63;
                    size_t head = (size_t)(bb * HH + hh) << 16;
                    size_t off;
                    if (mode == 0) {
                        off = head + (((size_t)(s >> 4) * 2 + (d >> 5)) * 64
                              + ((d >> 3) & 3) * 16 + (s & 15)) * 8 + (d & 7);
                    } else {
                        off = head + (((size_t)(s >> 5) * 4 + (d >> 4)) * 64
                              + ((s >> 3) & 3) * 16 + (d & 15)) * 8 + (s & 7);
                    }
                    ((unsigned short*)out)[off] = f2bf(v);
                }
            }
        }
}

// SCL = (1/8) * log2(e), folded into Q at projection time
#define SCLQ 0.18033688f

__global__ __launch_bounds__(256, 3) void gemm_qkv(
    const unsigned short* __restrict__ xq, const unsigned short* __restrict__ xk,
    const unsigned short* __restrict__ xv,
    const unsigned short* __restrict__ wtq, const unsigned short* __restrict__ wtk,
    const unsigned short* __restrict__ wtv,
    const float* __restrict__ bq, const float* __restrict__ bk, const float* __restrict__ bv,
    unsigned short* __restrict__ q, unsigned short* __restrict__ k, unsigned short* __restrict__ v)
{
    __shared__ unsigned short pool[16384];   // 32 KB: As/Bs for BK=64
    // XCD-bijective swizzle: 768 wgs, each XCD gets a contiguous (z,y-range,all-x) chunk
    int bid = blockIdx.x;
    int swz = (bid & 7) * 96 + (bid >> 3);
    int z = swz >> 8, rem = swz & 255;
    int n0 = (rem & 7) * 128, m0 = (rem >> 3) * 128;
    const unsigned short* A  = z == 0 ? xq  : (z == 1 ? xk  : xv);
    const unsigned short* Bt = z == 0 ? wtq : (z == 1 ? wtk : wtv);
    const float* bias        = z == 0 ? bq  : (z == 1 ? bk  : bv);
    void* out                = z == 0 ? (void*)q : (z == 1 ? (void*)k : (void*)v);
    gemm128_core<64>(pool, pool + 8192, A, Bt, bias, out, z == 2 ? 1 : 0,
                     z == 0 ? SCLQ : 1.0f, m0, n0);
}

// standalone gemm_o (fallback path)
__global__ __launch_bounds__(256, 3) void gemm_o(
    const unsigned short* __restrict__ x, const unsigned short* __restrict__ wto,
    const float* __restrict__ bo, float* __restrict__ out)
{
    __shared__ unsigned short pool[16384];
    int bid = blockIdx.x;
    int swz = (bid & 7) * 32 + (bid >> 3);
    int n0 = (swz & 7) * 128, m0 = (swz >> 3) * 128;
    gemm128_core<64>(pool, pool + 8192, x, wto, bo, out, 2, 1.0f, m0, n0);
}

// =========================================================================
// FAST PATH: fused flash attention (no P materialization)
//   fattn_kernel : 512 thr, KVBLK=64 dbuf LDS K/V staging, single barrier/iter
//   tail_kernel  : attc (LDS-staged K) + gemm_o (BK=64) fused, LDS union
// Q/K frag layout (mode 0): chunk=(s>>4)*2+(d>>5); lane=((d>>3)&3)*16+(s&15); e=d&7
// V   frag layout (mode 1): chunk=(s>>5)*4+(d>>4); lane=((s>>3)&3)*16+(d&15); e=s&7
// =========================================================================

__global__ __launch_bounds__(512, 4) void fattn_kernel(
    const unsigned short* __restrict__ qf, const unsigned short* __restrict__ kf,
    const unsigned short* __restrict__ vf, float* __restrict__ Z,
    unsigned short* __restrict__ xat)
{
    __shared__ __align__(16) unsigned short kls[2][4096];   // 2 x 8 KB: K 64-row tile dbuf
    __shared__ __align__(16) unsigned short vls[2][4096];   // 2 x 8 KB: V 64-row tile dbuf
    __shared__ __align__(16) unsigned short plds[8][640];   // wave-private P transpose
    int t = threadIdx.x, w = t >> 6, lane = t & 63, quad = lane >> 4, l15 = lane & 15;
    // XCD swizzle: all 8 q-blocks of one (b,h) on the same XCD (K/V L2-resident)
    int bid = blockIdx.x;
    int swz = (bid & 7) * 64 + (bid >> 3);
    int bh = swz >> 3, m0 = (swz & 7) * 128;
    int b = bh >> 4, h = bh & 15;
    const unsigned short* qh = qf + ((size_t)bh << 16);
    const unsigned short* kh = kf + ((size_t)bh << 16);
    const unsigned short* vh = vf + ((size_t)bh << 16);

    // one q16 tile per wave; Q held in registers (pre-scaled by SCLQ)
    bf16x8 qfrag[2];
    int s16b = (m0 >> 4) + w;
#pragma unroll
    for (int dh = 0; dh < 2; dh++)
        qfrag[dh] = *(const bf16x8*)(qh + (size_t)(s16b * 2 + dh) * 512 + lane * 8);

    f32x4 zero = {0.f, 0.f, 0.f, 0.f};
    f32x4 oacc[4];
#pragma unroll
    for (int ni = 0; ni < 4; ni++) oacc[ni] = zero;
    float zacc = 0.f;

    // staging role: thread stages K chunk w and V chunk w of the 8-chunk pair tile
    const unsigned short* ksrc = kh + (size_t)w * 512 + lane * 8;
    const unsigned short* vsrc = vh + (size_t)w * 512 + lane * 8;
    int koff = w * 512 + lane * 8;

    // prologue: stage pair 0 into buf 0
    gload_lds16(ksrc, kls[0] + koff);
    gload_lds16(vsrc, vls[0] + koff);
    __syncthreads();

    int cur = 0;
    for (int p = 0; p < 16; p++) {            // 64 k-rows per iteration
        // issue next pair's stage FIRST; latency hides under 2 sub-tiles of compute
        if (p < 15) {
            gload_lds16(ksrc + (size_t)(p + 1) * 4096, kls[cur ^ 1] + koff);
            gload_lds16(vsrc + (size_t)(p + 1) * 4096, vls[cur ^ 1] + koff);
        }

#pragma unroll
        for (int sub = 0; sub < 2; sub++) {   // two 32-row sub-tiles
            bf16x8 kc[4], vc[4];
#pragma unroll
            for (int i = 0; i < 4; i++) {
                kc[i] = *(const bf16x8*)&kls[cur][(sub * 4 + i) * 512 + lane * 8];
                vc[i] = *(const bf16x8*)&vls[cur][(sub * 4 + i) * 512 + lane * 8];
            }

            // S^T = K . Q^T : lane col=q=l15, rows k = si*16 + quad*4 + r
            f32x4 st[2];
#pragma unroll
            for (int si = 0; si < 2; si++) {
                st[si] = __builtin_amdgcn_mfma_f32_16x16x32_bf16(kc[si * 2 + 0], qfrag[0], zero, 0, 0, 0);
                st[si] = __builtin_amdgcn_mfma_f32_16x16x32_bf16(kc[si * 2 + 1], qfrag[1], st[si], 0, 0, 0);
            }

            // exp2, row-sum partials, pack pairs -> wave-private LDS [q][k] tile
#pragma unroll
            for (int si = 0; si < 2; si++) {
                float p0 = exp2f(st[si][0]);
                float p1 = exp2f(st[si][1]);
                float p2 = exp2f(st[si][2]);
                float p3 = exp2f(st[si][3]);
                zacc += (p0 + p1) + (p2 + p3);
                unsigned int pk0 = (unsigned int)f2bf(p0) | ((unsigned int)f2bf(p1) << 16);
                unsigned int pk1 = (unsigned int)f2bf(p2) | ((unsigned int)f2bf(p3) << 16);
                *(uint2*)&plds[w][l15 * 40 + si * 16 + quad * 4] = make_uint2(pk0, pk1);
            }
            // read back as PV A-fragment (row=q=l15, k = quad*8..+7)
            bf16x8 pa = *(const bf16x8*)&plds[w][l15 * 40 + quad * 8];

            // O += P . V
#pragma unroll
            for (int ni = 0; ni < 4; ni++)
                oacc[ni] = __builtin_amdgcn_mfma_f32_16x16x32_bf16(pa, vc[ni], oacc[ni], 0, 0, 0);
        }

        // single barrier per pair: built-in vmcnt/lgkm drain completes the stage
        __syncthreads();
        cur ^= 1;
    }

    // exact Z per q-row (reduce across quads), write once — no atomics
    float zt = zacc;
    zt += __shfl_xor(zt, 16);
    zt += __shfl_xor(zt, 32);                  // all lanes: Z for q = base + l15
    if (quad == 0)
        Z[(size_t)bh * 1024 + m0 + w * 16 + l15] = zt;

    // O / Z -> xat[b,s,d]
#pragma unroll
    for (int r = 0; r < 4; r++) {
        int qrow = quad * 4 + r;
        float iz = 1.f / __shfl(zt, qrow);
        int q = m0 + w * 16 + qrow;
#pragma unroll
        for (int ni = 0; ni < 4; ni++)
            xat[((size_t)(b * 1024 + q)) * 1024 + h * 64 + ni * 16 + l15] =
                f2bf(oacc[ni][r] * iz);
    }
}

// ---- tail: attc (blocks 0..511) + gemm_o BK=64 (blocks 512..767), LDS union ----
__global__ __launch_bounds__(256, 3) void tail_kernel(
    const unsigned short* __restrict__ qf, const unsigned short* __restrict__ kf,
    const float* __restrict__ Z, const float* __restrict__ Wc,
    const float* __restrict__ bcp, float* __restrict__ attc,
    const unsigned short* __restrict__ xat, const unsigned short* __restrict__ wto,
    const float* __restrict__ bo, float* __restrict__ out0)
{
    __shared__ __align__(16) unsigned short pool[16384];   // 32 KB, branch-exclusive
    if (blockIdx.x >= 512) {
        // ---- gemm_o (BK=64, 32 KB from pool) ----
        int bid2 = blockIdx.x - 512;
        int swz = (bid2 & 7) * 32 + (bid2 >> 3);
        int n0 = (swz & 7) * 128, m0 = (swz >> 3) * 128;
        gemm128_core<64>(pool, pool + 8192, xat, wto, bo, out0, 2, 1.0f, m0, n0);
        return;
    }
    // ---- attc: recompute S per (b, q16-per-wave, k128), inner h loop ----
    // K tile (16KB per h, shared by all 4 waves) staged in pool, dbuf over h.
    unsigned short* ks0 = pool;
    unsigned short* ks1 = pool + 8192;
    int t = threadIdx.x, w = t >> 6, lane = t & 63, quad = lane >> 4, l15 = lane & 15;
    int bid = blockIdx.x;
    int u = (bid & 7) * 64 + (bid >> 3);   // bijective over 0..511
    int kb = u & 7, qg = (u >> 3) & 15, b = u >> 7;
    int qt = qg * 4 + w;                   // this wave's q16 tile
    int q = qt * 16 + l15;                 // this lane's q (swapped-C col)
    float bc = *bcp;
    f32x4 zero = {0.f, 0.f, 0.f, 0.f};
    f32x4 acc[4][2];
#pragma unroll
    for (int kt = 0; kt < 4; kt++)
#pragma unroll
        for (int si = 0; si < 2; si++) acc[kt][si] = zero;

    // preload all 16 per-h scalars (breaks 16 serial dependent loads)
    float wzv[16];
#pragma unroll
    for (int h = 0; h < 16; h++)
        wzv[h] = Wc[h] / Z[(size_t)(b * 16 + h) * 1024 + q];

    // stage h=0 K tile
    {
        const unsigned short* src = kf + ((size_t)(b * 16) << 16) + (size_t)(kb * 16) * 512;
#pragma unroll
        for (int i = 0; i < 4; i++) {
            int c = w + i * 4;
            gload_lds16(src + (size_t)c * 512 + lane * 8, ks0 + c * 512 + lane * 8);
        }
    }
    __syncthreads();

    int cb = 0;
    for (int h = 0; h < 16; h++) {
        int bh = b * 16 + h;
        const unsigned short* qh = qf + ((size_t)bh << 16);
        bf16x8 qfr0 = *(const bf16x8*)(qh + (size_t)(qt * 2 + 0) * 512 + lane * 8);
        bf16x8 qfr1 = *(const bf16x8*)(qh + (size_t)(qt * 2 + 1) * 512 + lane * 8);
        if (h < 15) {
            const unsigned short* src = kf + ((size_t)(bh + 1) << 16) + (size_t)(kb * 16) * 512;
            unsigned short* dst = (cb ? ks0 : ks1);
#pragma unroll
            for (int i = 0; i < 4; i++) {
                int c = w + i * 4;
                gload_lds16(src + (size_t)c * 512 + lane * 8, dst + c * 512 + lane * 8);
            }
        }
        const unsigned short* cbuf = (cb ? ks1 : ks0);
        float wz = wzv[h];
#pragma unroll
        for (int kt = 0; kt < 4; kt++) {
            bf16x8 kfr[4];
#pragma unroll
            for (int i = 0; i < 4; i++)
                kfr[i] = *(const bf16x8*)&cbuf[(size_t)(kt * 4 + i) * 512 + lane * 8];
#pragma unroll
            for (int si = 0; si < 2; si++) {
                f32x4 st = __builtin_amdgcn_mfma_f32_16x16x32_bf16(kfr[si * 2 + 0], qfr0, zero, 0, 0, 0);
                st = __builtin_amdgcn_mfma_f32_16x16x32_bf16(kfr[si * 2 + 1], qfr1, st, 0, 0, 0);
#pragma unroll
                for (int r = 0; r < 4; r++)
                    acc[kt][si][r] += wz * exp2f(st[r]);
            }
        }
        __syncthreads();   // waves done reading cbuf; stage(h+1) drained
        cb ^= 1;
    }
    // store: k = kb*128 + kt*32 + si*16 + quad*4 + r  (float4 along k)
#pragma unroll
    for (int kt = 0; kt < 4; kt++)
#pragma unroll
        for (int si = 0; si < 2; si++) {
            float4 vv = make_float4(acc[kt][si][0] + bc, acc[kt][si][1] + bc,
                                    acc[kt][si][2] + bc, acc[kt][si][3] + bc);
            *(float4*)(attc + ((size_t)(b * 1024 + q)) * 1024 + kb * 128 + kt * 32 + si * 16 + quad * 4) = vv;
        }
}

// =========================================================================
// FALLBACK: R5 fused attention (used when ws_size < fast-path requirement)
// =========================================================================
#define LDK(f) (*(const bf16x8*)(kh + ((size_t)(f) * 64 + lane) * 8))
#define LDV(f) (*(const bf16x8*)(vh + ((size_t)(f) * 64 + lane) * 8))

__global__ __launch_bounds__(1024, 4) void attn_kernel(
    const unsigned short* __restrict__ qf, const unsigned short* __restrict__ kf,
    const unsigned short* __restrict__ vf, const float* __restrict__ Wc,
    const float* __restrict__ bcp, unsigned short* __restrict__ xout,
    float* __restrict__ attc)
{
    __shared__ float accc[16][1028];
    __shared__ unsigned short tsc[16][16][36];

    int t = threadIdx.x, w = t >> 6, lane = t & 63, quad = lane >> 4, l15 = lane & 15;
    int b = blockIdx.x >> 6, qt = blockIdx.x & 63;
    int h = w;

    for (int i = t; i < 16 * 1028; i += 1024) (&accc[0][0])[i] = 0.f;
    __syncthreads();

    const unsigned short* qh = qf + ((size_t)(b * HH + h) << 16);
    const unsigned short* kh = kf + ((size_t)(b * HH + h) << 16);
    const unsigned short* vh = vf + ((size_t)(b * HH + h) << 16);
    float wc = Wc[h], bc = *bcp;
    f32x4 zero = {0.f, 0.f, 0.f, 0.f};

    bf16x8 a0 = *(const bf16x8*)(qh + ((size_t)(qt * 2 + 0) * 64 + lane) * 8);
    bf16x8 a1 = *(const bf16x8*)(qh + ((size_t)(qt * 2 + 1) * 64 + lane) * 8);

    float rs[4] = {0.f, 0.f, 0.f, 0.f};
    bf16x8 c0 = LDK(0), c1 = LDK(1), c2 = LDK(2), c3 = LDK(3);
    PIN4(c0, c1, c2, c3);
    bf16x8 d0 = LDK(4), d1 = LDK(5), d2 = LDK(6), d3 = LDK(7);
    PIN4(d0, d1, d2, d3);
#pragma unroll 2
    for (int g = 0; g < 32; g++) {
        int gn = g < 30 ? g + 2 : 31;
        bf16x8 n0 = LDK(gn * 4 + 0), n1 = LDK(gn * 4 + 1);
        bf16x8 n2 = LDK(gn * 4 + 2), n3 = LDK(gn * 4 + 3);
        PIN4(n0, n1, n2, n3);
        f32x4 s0 = zero, s1 = zero;
        s0 = __builtin_amdgcn_mfma_f32_16x16x32_bf16(a0, c0, s0, 0, 0, 0);
        s0 = __builtin_amdgcn_mfma_f32_16x16x32_bf16(a1, c1, s0, 0, 0, 0);
        s1 = __builtin_amdgcn_mfma_f32_16x16x32_bf16(a0, c2, s1, 0, 0, 0);
        s1 = __builtin_amdgcn_mfma_f32_16x16x32_bf16(a1, c3, s1, 0, 0, 0);
#pragma unroll
        for (int r = 0; r < 4; r++) rs[r] += exp2f(s0[r]) + exp2f(s1[r]);
        c0 = d0; c1 = d1; c2 = d2; c3 = d3;
        d0 = n0; d1 = n1; d2 = n2; d3 = n3;
    }
#pragma unroll
    for (int r = 0; r < 4; r++) {
        rs[r] += __shfl_xor(rs[r], 1);
        rs[r] += __shfl_xor(rs[r], 2);
        rs[r] += __shfl_xor(rs[r], 4);
        rs[r] += __shfl_xor(rs[r], 8);
    }
    float invC[4], sC[4];
#pragma unroll
    for (int r = 0; r < 4; r++) { invC[r] = 1.f / rs[r]; sC[r] = wc * invC[r]; }

    f32x4 o0 = zero, o1 = zero, o2 = zero, o3 = zero;
    int cc0 = (2 * w) & 31;
    bf16x8 k0 = LDK(cc0 * 4 + 0), k1 = LDK(cc0 * 4 + 1);
    bf16x8 k2 = LDK(cc0 * 4 + 2), k3 = LDK(cc0 * 4 + 3);
    PIN4(k0, k1, k2, k3);
    bf16x8 v0 = LDV(cc0 * 4 + 0), v1 = LDV(cc0 * 4 + 1);
    bf16x8 v2 = LDV(cc0 * 4 + 2), v3 = LDV(cc0 * 4 + 3);
    PIN4(v0, v1, v2, v3);
#pragma unroll 2
    for (int i = 0; i < 32; i++) {
        int cc = (i + 2 * w) & 31;
        int cn = ((i + 1) + 2 * w) & 31;
        bf16x8 kn0 = LDK(cn * 4 + 0), kn1 = LDK(cn * 4 + 1);
        bf16x8 kn2 = LDK(cn * 4 + 2), kn3 = LDK(cn * 4 + 3);
        PIN4(kn0, kn1, kn2, kn3);
        bf16x8 vn0 = LDV(cn * 4 + 0), vn1 = LDV(cn * 4 + 1);
        bf16x8 vn2 = LDV(cn * 4 + 2), vn3 = LDV(cn * 4 + 3);
        PIN4(vn0, vn1, vn2, vn3);

        f32x4 s0 = zero, s1 = zero;
        s0 = __builtin_amdgcn_mfma_f32_16x16x32_bf16(a0, k0, s0, 0, 0, 0);
        s0 = __builtin_amdgcn_mfma_f32_16x16x32_bf16(a1, k1, s0, 0, 0, 0);
        s1 = __builtin_amdgcn_mfma_f32_16x16x32_bf16(a0, k2, s1, 0, 0, 0);
        s1 = __builtin_amdgcn_mfma_f32_16x16x32_bf16(a1, k3, s1, 0, 0, 0);

#pragma unroll
        for (int r = 0; r < 4; r++) {
            float p0 = exp2f(s0[r]);
            float p1 = exp2f(s1[r]);
            int row = quad * 4 + r;
            tsc[w][row][l15] = f2bf(p0);
            tsc[w][row][16 + l15] = f2bf(p1);
            atomicAdd(&accc[row][cc * 32 + l15], sC[r] * p0);
            atomicAdd(&accc[row][cc * 32 + 16 + l15], sC[r] * p1);
        }
        bf16x8 ap = *(const bf16x8*)&tsc[w][l15][quad * 8];

        o0 = __builtin_amdgcn_mfma_f32_16x16x32_bf16(ap, v0, o0, 0, 0, 0);
        o1 = __builtin_amdgcn_mfma_f32_16x16x32_bf16(ap, v1, o1, 0, 0, 0);
        o2 = __builtin_amdgcn_mfma_f32_16x16x32_bf16(ap, v2, o2, 0, 0, 0);
        o3 = __builtin_amdgcn_mfma_f32_16x16x32_bf16(ap, v3, o3, 0, 0, 0);
        k0 = kn0; k1 = kn1; k2 = kn2; k3 = kn3;
        v0 = vn0; v1 = vn1; v2 = vn2; v3 = vn3;
    }

    f32x4 oo[4] = {o0, o1, o2, o3};
#pragma unroll
    for (int j = 0; j < 4; j++)
#pragma unroll
        for (int r = 0; r < 4; r++) {
            int row = quad * 4 + r;
            xout[((size_t)(b * SS) + qt * 16 + row) * DD + h * 64 + j * 16 + l15] =
                f2bf(oo[j][r] * invC[r]);
        }

    __syncthreads();
    for (int i = t; i < 16 * 1024; i += 1024) {
        int row = i >> 10, col = i & 1023;
        attc[((size_t)b * SS + qt * 16 + row) * SS + col] = accc[row][col] + bc;
    }
}

extern "C" void kernel_launch(void* const* d_in, const int* in_sizes, int n_in,
                              void* d_out, int out_size, void* d_ws, size_t ws_size,
                              hipStream_t stream) {
    const float* query = (const float*)d_in[0];
    const float* key   = (const float*)d_in[1];
    const float* value = (const float*)d_in[2];
    const float* Wq = (const float*)d_in[3];
    const float* bq = (const float*)d_in[4];
    const float* Wk = (const float*)d_in[5];
    const float* bk = (const float*)d_in[6];
    const float* Wv = (const float*)d_in[7];
    const float* bv = (const float*)d_in[8];
    const float* Wo = (const float*)d_in[9];
    const float* bo = (const float*)d_in[10];
    const float* Wc = (const float*)d_in[11];
    const float* bc = (const float*)d_in[12];

    unsigned short* ws  = (unsigned short*)d_ws;
    unsigned short* xq  = ws;
    unsigned short* xk  = xq  + (size_t)4194304;
    unsigned short* xv  = xk  + (size_t)4194304;
    unsigned short* wtq = xv  + (size_t)4194304;
    unsigned short* wtk = wtq + (size_t)1048576;
    unsigned short* wtv = wtk + (size_t)1048576;
    unsigned short* wto = wtv + (size_t)1048576;
    unsigned short* qfb = wto + (size_t)1048576;    // Q frag-blocked (pre-scaled)
    unsigned short* kfb = qfb + (size_t)4194304;    // K frag-blocked
    unsigned short* vfb = kfb + (size_t)4194304;    // V frag-blocked
    unsigned short* xat = vfb + (size_t)4194304;    // [b,s,d]

    float* out0 = (float*)d_out;
    float* attc = out0 + (size_t)4194304;

    // fast-path extra workspace: Z only (256KB)
    const size_t base_bytes = 67108864;             // 32M ushorts above
    const size_t z_bytes = 262144;
    bool fast = ws_size >= base_bytes + z_bytes;

    hipLaunchKernelGGL(prep, dim3(8192), dim3(256), 0, stream,
                       query, key, value, xq, xk, xv,
                       Wq, Wk, Wv, Wo, wtq, wtk, wtv, wto);
    hipLaunchKernelGGL(gemm_qkv, dim3(768), dim3(256), 0, stream,
                       xq, xk, xv, wtq, wtk, wtv, bq, bk, bv, qfb, kfb, vfb);

    if (fast) {
        float* Zbuf = (float*)((char*)d_ws + base_bytes);
        hipLaunchKernelGGL(fattn_kernel, dim3(512), dim3(512), 0, stream,
                           qfb, kfb, vfb, Zbuf, xat);
        hipLaunchKernelGGL(tail_kernel, dim3(768), dim3(256), 0, stream,
                           qfb, kfb, Zbuf, Wc, bc, attc,
                           xat, wto, bo, out0);
    } else {
        hipLaunchKernelGGL(attn_kernel, dim3(256), dim3(1024), 0, stream,
                           qfb, kfb, vfb, Wc, bc, xat, attc);
        hipLaunchKernelGGL(gemm_o, dim3(256), dim3(256), 0, stream,
                           xat, wto, bo, out0);
    }
}

// Round 10
// 223.583 us; speedup vs baseline: 1.0736x; 1.0736x over previous
//
#include <hip/hip_runtime.h>
#include <hip/hip_bf16.h>

// Problem constants: B=4, S=1024, D=1024, H=16, HD=64
#define SS 1024
#define DD 1024
#define HH 16
#define HDh 64

typedef short bf16x8 __attribute__((ext_vector_type(8)));
typedef float f32x4 __attribute__((ext_vector_type(4)));

__device__ inline unsigned short f2bf(float f) {
    union { __hip_bfloat16 h; unsigned short u; } cv;
    cv.h = __float2bfloat16(f);   // RTNE
    return cv.u;
}
__device__ inline float bf2f(short u) {
    unsigned int x = ((unsigned int)(unsigned short)u) << 16;
    return __uint_as_float(x);
}

#define PIN4(a, b, c, d) asm volatile("" : "+v"(a), "+v"(b), "+v"(c), "+v"(d))

// async global->LDS, 16B per lane; LDS dest = wave-uniform base + lane*16
__device__ inline void gload_lds16(const unsigned short* g, unsigned short* l) {
    __builtin_amdgcn_global_load_lds(
        (const __attribute__((address_space(1))) unsigned int*)g,
        (__attribute__((address_space(3))) unsigned int*)l, 16, 0, 0);
}

// ---------------- prep: fused cvt3 (blocks 0..4095) + wtrans (4096..8191) ----------------
__global__ __launch_bounds__(256) void prep(
    const float* __restrict__ a, const float* __restrict__ b, const float* __restrict__ c,
    unsigned short* __restrict__ oa, unsigned short* __restrict__ ob, unsigned short* __restrict__ oc,
    const float* __restrict__ Wq, const float* __restrict__ Wk,
    const float* __restrict__ Wv, const float* __restrict__ Wo,
    unsigned short* __restrict__ oq, unsigned short* __restrict__ okk,
    unsigned short* __restrict__ ov, unsigned short* __restrict__ oo)
{
    __shared__ float tile[32][33];
    int bid = blockIdx.x;
    if (bid < 4096) {
        size_t i = ((size_t)bid * 256 + threadIdx.x) * 4;
        float4 va = *(const float4*)(a + i);
        float4 vb = *(const float4*)(b + i);
        float4 vc = *(const float4*)(c + i);
        *(ushort4*)(oa + i) = make_ushort4(f2bf(va.x), f2bf(va.y), f2bf(va.z), f2bf(va.w));
        *(ushort4*)(ob + i) = make_ushort4(f2bf(vb.x), f2bf(vb.y), f2bf(vb.z), f2bf(vb.w));
        *(ushort4*)(oc + i) = make_ushort4(f2bf(vc.x), f2bf(vc.y), f2bf(vc.z), f2bf(vc.w));
    } else {
        int idx = bid - 4096;
        int z = idx >> 10;
        const float* W = z == 0 ? Wq : (z == 1 ? Wk : (z == 2 ? Wv : Wo));
        unsigned short* O = z == 0 ? oq : (z == 1 ? okk : (z == 2 ? ov : oo));
        int e0 = (idx & 31) * 32, d0 = ((idx >> 5) & 31) * 32;
        int r = threadIdx.x >> 3, c4 = (threadIdx.x & 7) * 4;
        float4 v = *(const float4*)(W + (size_t)(d0 + r) * DD + e0 + c4);
        tile[r][c4 + 0] = v.x; tile[r][c4 + 1] = v.y; tile[r][c4 + 2] = v.z; tile[r][c4 + 3] = v.w;
        __syncthreads();
        ushort4 u = make_ushort4(f2bf(tile[c4 + 0][r]), f2bf(tile[c4 + 1][r]),
                                 f2bf(tile[c4 + 2][r]), f2bf(tile[c4 + 3][r]));
        *(ushort4*)(O + (size_t)(e0 + r) * DD + d0 + c4) = u;
    }
}

// ---------------- 128x128 bf16 MFMA GEMM core, m97 2-barrier shape, templated BK ----------------
// INTERNAL __shared__ (R9's caller-pool variant defeated LDS addrspace inference:
// FETCH 22.6->45MB, WRITE 24.6->69MB, dur 41.6->51us — do not externalize).
template<int BK>
__device__ inline void gemm128_core(const unsigned short* __restrict__ A,
                                    const unsigned short* __restrict__ Bt,
                                    const float* __restrict__ bias,
                                    void* __restrict__ out, int mode, float oscale,
                                    int m0, int n0)
{
    __shared__ unsigned short As[128 * BK];
    __shared__ unsigned short Bs[128 * BK];
    int t = threadIdx.x;
    int w = t >> 6, lane = t & 63, quad = lane >> 4, l15 = lane & 15;
    int wm = w >> 1, wn = w & 1;

    f32x4 zero = {0.f, 0.f, 0.f, 0.f};
    f32x4 acc[4][4];
#pragma unroll
    for (int i = 0; i < 4; i++)
#pragma unroll
        for (int j = 0; j < 4; j++) acc[i][j] = zero;

    for (int k0 = 0; k0 < DD; k0 += BK) {
        __syncthreads();
        if constexpr (BK == 32) {
#pragma unroll
            for (int i = 0; i < 4; i++) {
                int chunk = w + i * 4;            // 0..15
                int half = chunk >> 3;            // 0=A, 1=B
                int c = chunk & 7;                // 16-row chunk within matrix
                const unsigned short* g = (half ? Bt : A)
                    + (size_t)((half ? n0 : m0) + c * 16 + (lane >> 2)) * DD + k0 + (lane & 3) * 8;
                unsigned short* l = (half ? Bs : As) + c * 512 + lane * 8;
                gload_lds16(g, l);
            }
        } else {
#pragma unroll
            for (int i = 0; i < 8; i++) {
                int chunk = w + i * 4;            // 0..31
                int half = chunk >> 4;            // 0=A, 1=B
                int sub = chunk & 15;             // 1KB subchunk: (rowchunk, khalf)
                const unsigned short* g = (half ? Bt : A)
                    + (size_t)((half ? n0 : m0) + (sub >> 1) * 16 + (lane >> 2)) * DD
                    + k0 + (sub & 1) * 32 + (lane & 3) * 8;
                unsigned short* l = (half ? Bs : As) + sub * 512 + lane * 8;
                gload_lds16(g, l);
            }
        }
        __syncthreads();
        if constexpr (BK == 32) {
            bf16x8 af[4], bfr[4];
#pragma unroll
            for (int mi = 0; mi < 4; mi++)
                af[mi] = *(const bf16x8*)&As[(wm * 64 + mi * 16 + l15) * 32 + quad * 8];
#pragma unroll
            for (int ni = 0; ni < 4; ni++)
                bfr[ni] = *(const bf16x8*)&Bs[(wn * 64 + ni * 16 + l15) * 32 + quad * 8];
#pragma unroll
            for (int mi = 0; mi < 4; mi++)
#pragma unroll
                for (int ni = 0; ni < 4; ni++)
                    acc[mi][ni] = __builtin_amdgcn_mfma_f32_16x16x32_bf16(af[mi], bfr[ni], acc[mi][ni], 0, 0, 0);
        } else {
#pragma unroll
            for (int kk = 0; kk < 2; kk++) {
                bf16x8 af[4], bfr[4];
#pragma unroll
                for (int mi = 0; mi < 4; mi++)
                    af[mi] = *(const bf16x8*)&As[((wm * 4 + mi) * 2 + kk) * 512 + l15 * 32 + quad * 8];
#pragma unroll
                for (int ni = 0; ni < 4; ni++)
                    bfr[ni] = *(const bf16x8*)&Bs[((wn * 4 + ni) * 2 + kk) * 512 + l15 * 32 + quad * 8];
#pragma unroll
                for (int mi = 0; mi < 4; mi++)
#pragma unroll
                    for (int ni = 0; ni < 4; ni++)
                        acc[mi][ni] = __builtin_amdgcn_mfma_f32_16x16x32_bf16(af[mi], bfr[ni], acc[mi][ni], 0, 0, 0);
            }
        }
    }

#pragma unroll
    for (int mi = 0; mi < 4; mi++)
#pragma unroll
        for (int ni = 0; ni < 4; ni++) {
            int n = n0 + wn * 64 + ni * 16 + l15;
            float bv = bias[n];
#pragma unroll
            for (int r = 0; r < 4; r++) {
                int m = m0 + wm * 64 + mi * 16 + quad * 4 + r;
                float v = (acc[mi][ni][r] + bv) * oscale;
                if (mode == 2) {
                    ((float*)out)[(size_t)m * DD + n] = v;
                } else {
                    int bb = m >> 10, s = m & 1023, hh = n >> 6, d = n & 63;
                    size_t head = (size_t)(bb * HH + hh) << 16;
                    size_t off;
                    if (mode == 0) {
                        off = head + (((size_t)(s >> 4) * 2 + (d >> 5)) * 64
                              + ((d >> 3) & 3) * 16 + (s & 15)) * 8 + (d & 7);
                    } else {
                        off = head + (((size_t)(s >> 5) * 4 + (d >> 4)) * 64
                              + ((s >> 3) & 3) * 16 + (d & 15)) * 8 + (s & 7);
                    }
                    ((unsigned short*)out)[off] = f2bf(v);
                }
            }
        }
}

// SCL = (1/8) * log2(e), folded into Q at projection time
#define SCLQ 0.18033688f

__global__ __launch_bounds__(256, 3) void gemm_qkv(
    const unsigned short* __restrict__ xq, const unsigned short* __restrict__ xk,
    const unsigned short* __restrict__ xv,
    const unsigned short* __restrict__ wtq, const unsigned short* __restrict__ wtk,
    const unsigned short* __restrict__ wtv,
    const float* __restrict__ bq, const float* __restrict__ bk, const float* __restrict__ bv,
    unsigned short* __restrict__ q, unsigned short* __restrict__ k, unsigned short* __restrict__ v)
{
    // XCD-bijective swizzle: 768 wgs, each XCD gets a contiguous (z,y-range,all-x) chunk
    int bid = blockIdx.x;
    int swz = (bid & 7) * 96 + (bid >> 3);
    int z = swz >> 8, rem = swz & 255;
    int n0 = (rem & 7) * 128, m0 = (rem >> 3) * 128;
    const unsigned short* A  = z == 0 ? xq  : (z == 1 ? xk  : xv);
    const unsigned short* Bt = z == 0 ? wtq : (z == 1 ? wtk : wtv);
    const float* bias        = z == 0 ? bq  : (z == 1 ? bk  : bv);
    void* out                = z == 0 ? (void*)q : (z == 1 ? (void*)k : (void*)v);
    gemm128_core<64>(A, Bt, bias, out, z == 2 ? 1 : 0, z == 0 ? SCLQ : 1.0f, m0, n0);
}

// standalone gemm_o (fallback path)
__global__ __launch_bounds__(256, 3) void gemm_o(
    const unsigned short* __restrict__ x, const unsigned short* __restrict__ wto,
    const float* __restrict__ bo, float* __restrict__ out)
{
    int bid = blockIdx.x;
    int swz = (bid & 7) * 32 + (bid >> 3);
    int n0 = (swz & 7) * 128, m0 = (swz >> 3) * 128;
    gemm128_core<32>(x, wto, bo, out, 2, 1.0f, m0, n0);
}

// =========================================================================
// FAST PATH: fused flash attention (no P materialization)
//   fattn_kernel : 512 thr, KVBLK=64 dbuf LDS K/V staging, single barrier/iter
//   tail_kernel  : attc (LDS-staged K + reg-dbuf Q) + gemm_o (BK=32) fused
// Q/K frag layout (mode 0): chunk=(s>>4)*2+(d>>5); lane=((d>>3)&3)*16+(s&15); e=d&7
// V   frag layout (mode 1): chunk=(s>>5)*4+(d>>4); lane=((s>>3)&3)*16+(d&15); e=s&7
// =========================================================================

__global__ __launch_bounds__(512, 4) void fattn_kernel(
    const unsigned short* __restrict__ qf, const unsigned short* __restrict__ kf,
    const unsigned short* __restrict__ vf, float* __restrict__ Z,
    unsigned short* __restrict__ xat)
{
    __shared__ __align__(16) unsigned short kls[2][4096];   // 2 x 8 KB: K 64-row tile dbuf
    __shared__ __align__(16) unsigned short vls[2][4096];   // 2 x 8 KB: V 64-row tile dbuf
    __shared__ __align__(16) unsigned short plds[8][640];   // wave-private P transpose
    int t = threadIdx.x, w = t >> 6, lane = t & 63, quad = lane >> 4, l15 = lane & 15;
    // XCD swizzle: all 8 q-blocks of one (b,h) on the same XCD (K/V L2-resident)
    int bid = blockIdx.x;
    int swz = (bid & 7) * 64 + (bid >> 3);
    int bh = swz >> 3, m0 = (swz & 7) * 128;
    int b = bh >> 4, h = bh & 15;
    const unsigned short* qh = qf + ((size_t)bh << 16);
    const unsigned short* kh = kf + ((size_t)bh << 16);
    const unsigned short* vh = vf + ((size_t)bh << 16);

    // one q16 tile per wave; Q held in registers (pre-scaled by SCLQ)
    bf16x8 qfrag[2];
    int s16b = (m0 >> 4) + w;
#pragma unroll
    for (int dh = 0; dh < 2; dh++)
        qfrag[dh] = *(const bf16x8*)(qh + (size_t)(s16b * 2 + dh) * 512 + lane * 8);

    f32x4 zero = {0.f, 0.f, 0.f, 0.f};
    f32x4 oacc[4];
#pragma unroll
    for (int ni = 0; ni < 4; ni++) oacc[ni] = zero;
    float zacc = 0.f;

    // staging role: thread stages K chunk w and V chunk w of the 8-chunk pair tile
    const unsigned short* ksrc = kh + (size_t)w * 512 + lane * 8;
    const unsigned short* vsrc = vh + (size_t)w * 512 + lane * 8;
    int koff = w * 512 + lane * 8;

    // prologue: stage pair 0 into buf 0
    gload_lds16(ksrc, kls[0] + koff);
    gload_lds16(vsrc, vls[0] + koff);
    __syncthreads();

    int cur = 0;
    for (int p = 0; p < 16; p++) {            // 64 k-rows per iteration
        // issue next pair's stage FIRST; latency hides under 2 sub-tiles of compute
        if (p < 15) {
            gload_lds16(ksrc + (size_t)(p + 1) * 4096, kls[cur ^ 1] + koff);
            gload_lds16(vsrc + (size_t)(p + 1) * 4096, vls[cur ^ 1] + koff);
        }

#pragma unroll
        for (int sub = 0; sub < 2; sub++) {   // two 32-row sub-tiles
            bf16x8 kc[4], vc[4];
#pragma unroll
            for (int i = 0; i < 4; i++) {
                kc[i] = *(const bf16x8*)&kls[cur][(sub * 4 + i) * 512 + lane * 8];
                vc[i] = *(const bf16x8*)&vls[cur][(sub * 4 + i) * 512 + lane * 8];
            }

            // S^T = K . Q^T : lane col=q=l15, rows k = si*16 + quad*4 + r
            f32x4 st[2];
#pragma unroll
            for (int si = 0; si < 2; si++) {
                st[si] = __builtin_amdgcn_mfma_f32_16x16x32_bf16(kc[si * 2 + 0], qfrag[0], zero, 0, 0, 0);
                st[si] = __builtin_amdgcn_mfma_f32_16x16x32_bf16(kc[si * 2 + 1], qfrag[1], st[si], 0, 0, 0);
            }

            // exp2, row-sum partials, pack pairs -> wave-private LDS [q][k] tile
#pragma unroll
            for (int si = 0; si < 2; si++) {
                float p0 = exp2f(st[si][0]);
                float p1 = exp2f(st[si][1]);
                float p2 = exp2f(st[si][2]);
                float p3 = exp2f(st[si][3]);
                zacc += (p0 + p1) + (p2 + p3);
                unsigned int pk0 = (unsigned int)f2bf(p0) | ((unsigned int)f2bf(p1) << 16);
                unsigned int pk1 = (unsigned int)f2bf(p2) | ((unsigned int)f2bf(p3) << 16);
                *(uint2*)&plds[w][l15 * 40 + si * 16 + quad * 4] = make_uint2(pk0, pk1);
            }
            // read back as PV A-fragment (row=q=l15, k = quad*8..+7)
            bf16x8 pa = *(const bf16x8*)&plds[w][l15 * 40 + quad * 8];

            // O += P . V
#pragma unroll
            for (int ni = 0; ni < 4; ni++)
                oacc[ni] = __builtin_amdgcn_mfma_f32_16x16x32_bf16(pa, vc[ni], oacc[ni], 0, 0, 0);
        }

        // single barrier per pair: built-in vmcnt/lgkm drain completes the stage
        __syncthreads();
        cur ^= 1;
    }

    // exact Z per q-row (reduce across quads), write once — no atomics
    float zt = zacc;
    zt += __shfl_xor(zt, 16);
    zt += __shfl_xor(zt, 32);                  // all lanes: Z for q = base + l15
    if (quad == 0)
        Z[(size_t)bh * 1024 + m0 + w * 16 + l15] = zt;

    // O / Z -> xat[b,s,d]
#pragma unroll
    for (int r = 0; r < 4; r++) {
        int qrow = quad * 4 + r;
        float iz = 1.f / __shfl(zt, qrow);
        int q = m0 + w * 16 + qrow;
#pragma unroll
        for (int ni = 0; ni < 4; ni++)
            xat[((size_t)(b * 1024 + q)) * 1024 + h * 64 + ni * 16 + l15] =
                f2bf(oacc[ni][r] * iz);
    }
}

// ---- tail: attc (blocks 0..511, LDS K + reg-dbuf Q) + gemm_o BK=32 (512..767) ----
__global__ __launch_bounds__(256, 3) void tail_kernel(
    const unsigned short* __restrict__ qf, const unsigned short* __restrict__ kf,
    const float* __restrict__ Z, const float* __restrict__ Wc,
    const float* __restrict__ bcp, float* __restrict__ attc,
    const unsigned short* __restrict__ xat, const unsigned short* __restrict__ wto,
    const float* __restrict__ bo, float* __restrict__ out0)
{
    if (blockIdx.x >= 512) {
        // ---- gemm_o (256-thread blocks, full participation, 16 KB LDS) ----
        int bid2 = blockIdx.x - 512;
        int swz = (bid2 & 7) * 32 + (bid2 >> 3);
        int n0 = (swz & 7) * 128, m0 = (swz >> 3) * 128;
        gemm128_core<32>(xat, wto, bo, out0, 2, 1.0f, m0, n0);
        return;
    }
    // ---- attc: recompute S per (b, q16-per-wave, k128), inner h loop ----
    // K tile (16KB per h, shared by all 4 waves) staged in LDS, dbuf over h.
    __shared__ unsigned short ks[2][8192];
    int t = threadIdx.x, w = t >> 6, lane = t & 63, quad = lane >> 4, l15 = lane & 15;
    int bid = blockIdx.x;
    int u = (bid & 7) * 64 + (bid >> 3);   // bijective over 0..511
    int kb = u & 7, qg = (u >> 3) & 15, b = u >> 7;
    int qt = qg * 4 + w;                   // this wave's q16 tile
    int q = qt * 16 + l15;                 // this lane's q (swapped-C col)
    float bc = *bcp;
    f32x4 zero = {0.f, 0.f, 0.f, 0.f};
    f32x4 acc[4][2];
#pragma unroll
    for (int kt = 0; kt < 4; kt++)
#pragma unroll
        for (int si = 0; si < 2; si++) acc[kt][si] = zero;

    // preload all 16 per-h scalars (breaks 16 serial dependent loads)
    float wzv[16];
#pragma unroll
    for (int h = 0; h < 16; h++)
        wzv[h] = Wc[h] / Z[(size_t)(b * 16 + h) * 1024 + q];

    // stage h=0 K tile
    {
        const unsigned short* src = kf + ((size_t)(b * 16) << 16) + (size_t)(kb * 16) * 512;
#pragma unroll
        for (int i = 0; i < 4; i++) {
            int c = w + i * 4;
            gload_lds16(src + (size_t)c * 512 + lane * 8, ks[0] + c * 512 + lane * 8);
        }
    }
    // preload h=0 Q frags (reg double-buffer across h)
    const unsigned short* qh0 = qf + ((size_t)(b * 16) << 16);
    bf16x8 qc0 = *(const bf16x8*)(qh0 + (size_t)(qt * 2 + 0) * 512 + lane * 8);
    bf16x8 qc1 = *(const bf16x8*)(qh0 + (size_t)(qt * 2 + 1) * 512 + lane * 8);
    __syncthreads();

    int cb = 0;
    for (int h = 0; h < 16; h++) {
        int bh = b * 16 + h;
        // prefetch next h's Q frags + K tile; the end-of-iter barrier drains them
        bf16x8 qn0 = qc0, qn1 = qc1;
        if (h < 15) {
            const unsigned short* qhn = qf + ((size_t)(bh + 1) << 16);
            qn0 = *(const bf16x8*)(qhn + (size_t)(qt * 2 + 0) * 512 + lane * 8);
            qn1 = *(const bf16x8*)(qhn + (size_t)(qt * 2 + 1) * 512 + lane * 8);
            const unsigned short* src = kf + ((size_t)(bh + 1) << 16) + (size_t)(kb * 16) * 512;
#pragma unroll
            for (int i = 0; i < 4; i++) {
                int c = w + i * 4;
                gload_lds16(src + (size_t)c * 512 + lane * 8, ks[cb ^ 1] + c * 512 + lane * 8);
            }
        }
        float wz = wzv[h];
#pragma unroll
        for (int kt = 0; kt < 4; kt++) {
            bf16x8 kfr[4];
#pragma unroll
            for (int i = 0; i < 4; i++)
                kfr[i] = *(const bf16x8*)&ks[cb][(size_t)(kt * 4 + i) * 512 + lane * 8];
#pragma unroll
            for (int si = 0; si < 2; si++) {
                f32x4 st = __builtin_amdgcn_mfma_f32_16x16x32_bf16(kfr[si * 2 + 0], qc0, zero, 0, 0, 0);
                st = __builtin_amdgcn_mfma_f32_16x16x32_bf16(kfr[si * 2 + 1], qc1, st, 0, 0, 0);
#pragma unroll
                for (int r = 0; r < 4; r++)
                    acc[kt][si][r] += wz * exp2f(st[r]);
            }
        }
        __syncthreads();   // waves done reading ks[cb]; stage(h+1)+Q(h+1) drained
        cb ^= 1;
        qc0 = qn0; qc1 = qn1;
    }
    // store: k = kb*128 + kt*32 + si*16 + quad*4 + r  (float4 along k)
#pragma unroll
    for (int kt = 0; kt < 4; kt++)
#pragma unroll
        for (int si = 0; si < 2; si++) {
            float4 vv = make_float4(acc[kt][si][0] + bc, acc[kt][si][1] + bc,
                                    acc[kt][si][2] + bc, acc[kt][si][3] + bc);
            *(float4*)(attc + ((size_t)(b * 1024 + q)) * 1024 + kb * 128 + kt * 32 + si * 16 + quad * 4) = vv;
        }
}

// =========================================================================
// FALLBACK: R5 fused attention (used when ws_size < fast-path requirement)
// =========================================================================
#define LDK(f) (*(const bf16x8*)(kh + ((size_t)(f) * 64 + lane) * 8))
#define LDV(f) (*(const bf16x8*)(vh + ((size_t)(f) * 64 + lane) * 8))

__global__ __launch_bounds__(1024, 4) void attn_kernel(
    const unsigned short* __restrict__ qf, const unsigned short* __restrict__ kf,
    const unsigned short* __restrict__ vf, const float* __restrict__ Wc,
    const float* __restrict__ bcp, unsigned short* __restrict__ xout,
    float* __restrict__ attc)
{
    __shared__ float accc[16][1028];
    __shared__ unsigned short tsc[16][16][36];

    int t = threadIdx.x, w = t >> 6, lane = t & 63, quad = lane >> 4, l15 = lane & 15;
    int b = blockIdx.x >> 6, qt = blockIdx.x & 63;
    int h = w;

    for (int i = t; i < 16 * 1028; i += 1024) (&accc[0][0])[i] = 0.f;
    __syncthreads();

    const unsigned short* qh = qf + ((size_t)(b * HH + h) << 16);
    const unsigned short* kh = kf + ((size_t)(b * HH + h) << 16);
    const unsigned short* vh = vf + ((size_t)(b * HH + h) << 16);
    float wc = Wc[h], bc = *bcp;
    f32x4 zero = {0.f, 0.f, 0.f, 0.f};

    bf16x8 a0 = *(const bf16x8*)(qh + ((size_t)(qt * 2 + 0) * 64 + lane) * 8);
    bf16x8 a1 = *(const bf16x8*)(qh + ((size_t)(qt * 2 + 1) * 64 + lane) * 8);

    float rs[4] = {0.f, 0.f, 0.f, 0.f};
    bf16x8 c0 = LDK(0), c1 = LDK(1), c2 = LDK(2), c3 = LDK(3);
    PIN4(c0, c1, c2, c3);
    bf16x8 d0 = LDK(4), d1 = LDK(5), d2 = LDK(6), d3 = LDK(7);
    PIN4(d0, d1, d2, d3);
#pragma unroll 2
    for (int g = 0; g < 32; g++) {
        int gn = g < 30 ? g + 2 : 31;
        bf16x8 n0 = LDK(gn * 4 + 0), n1 = LDK(gn * 4 + 1);
        bf16x8 n2 = LDK(gn * 4 + 2), n3 = LDK(gn * 4 + 3);
        PIN4(n0, n1, n2, n3);
        f32x4 s0 = zero, s1 = zero;
        s0 = __builtin_amdgcn_mfma_f32_16x16x32_bf16(a0, c0, s0, 0, 0, 0);
        s0 = __builtin_amdgcn_mfma_f32_16x16x32_bf16(a1, c1, s0, 0, 0, 0);
        s1 = __builtin_amdgcn_mfma_f32_16x16x32_bf16(a0, c2, s1, 0, 0, 0);
        s1 = __builtin_amdgcn_mfma_f32_16x16x32_bf16(a1, c3, s1, 0, 0, 0);
#pragma unroll
        for (int r = 0; r < 4; r++) rs[r] += exp2f(s0[r]) + exp2f(s1[r]);
        c0 = d0; c1 = d1; c2 = d2; c3 = d3;
        d0 = n0; d1 = n1; d2 = n2; d3 = n3;
    }
#pragma unroll
    for (int r = 0; r < 4; r++) {
        rs[r] += __shfl_xor(rs[r], 1);
        rs[r] += __shfl_xor(rs[r], 2);
        rs[r] += __shfl_xor(rs[r], 4);
        rs[r] += __shfl_xor(rs[r], 8);
    }
    float invC[4], sC[4];
#pragma unroll
    for (int r = 0; r < 4; r++) { invC[r] = 1.f / rs[r]; sC[r] = wc * invC[r]; }

    f32x4 o0 = zero, o1 = zero, o2 = zero, o3 = zero;
    int cc0 = (2 * w) & 31;
    bf16x8 k0 = LDK(cc0 * 4 + 0), k1 = LDK(cc0 * 4 + 1);
    bf16x8 k2 = LDK(cc0 * 4 + 2), k3 = LDK(cc0 * 4 + 3);
    PIN4(k0, k1, k2, k3);
    bf16x8 v0 = LDV(cc0 * 4 + 0), v1 = LDV(cc0 * 4 + 1);
    bf16x8 v2 = LDV(cc0 * 4 + 2), v3 = LDV(cc0 * 4 + 3);
    PIN4(v0, v1, v2, v3);
#pragma unroll 2
    for (int i = 0; i < 32; i++) {
        int cc = (i + 2 * w) & 31;
        int cn = ((i + 1) + 2 * w) & 31;
        bf16x8 kn0 = LDK(cn * 4 + 0), kn1 = LDK(cn * 4 + 1);
        bf16x8 kn2 = LDK(cn * 4 + 2), kn3 = LDK(cn * 4 + 3);
        PIN4(kn0, kn1, kn2, kn3);
        bf16x8 vn0 = LDV(cn * 4 + 0), vn1 = LDV(cn * 4 + 1);
        bf16x8 vn2 = LDV(cn * 4 + 2), vn3 = LDV(cn * 4 + 3);
        PIN4(vn0, vn1, vn2, vn3);

        f32x4 s0 = zero, s1 = zero;
        s0 = __builtin_amdgcn_mfma_f32_16x16x32_bf16(a0, k0, s0, 0, 0, 0);
        s0 = __builtin_amdgcn_mfma_f32_16x16x32_bf16(a1, k1, s0, 0, 0, 0);
        s1 = __builtin_amdgcn_mfma_f32_16x16x32_bf16(a0, k2, s1, 0, 0, 0);
        s1 = __builtin_amdgcn_mfma_f32_16x16x32_bf16(a1, k3, s1, 0, 0, 0);

#pragma unroll
        for (int r = 0; r < 4; r++) {
            float p0 = exp2f(s0[r]);
            float p1 = exp2f(s1[r]);
            int row = quad * 4 + r;
            tsc[w][row][l15] = f2bf(p0);
            tsc[w][row][16 + l15] = f2bf(p1);
            atomicAdd(&accc[row][cc * 32 + l15], sC[r] * p0);
            atomicAdd(&accc[row][cc * 32 + 16 + l15], sC[r] * p1);
        }
        bf16x8 ap = *(const bf16x8*)&tsc[w][l15][quad * 8];

        o0 = __builtin_amdgcn_mfma_f32_16x16x32_bf16(ap, v0, o0, 0, 0, 0);
        o1 = __builtin_amdgcn_mfma_f32_16x16x32_bf16(ap, v1, o1, 0, 0, 0);
        o2 = __builtin_amdgcn_mfma_f32_16x16x32_bf16(ap, v2, o2, 0, 0, 0);
        o3 = __builtin_amdgcn_mfma_f32_16x16x32_bf16(ap, v3, o3, 0, 0, 0);
        k0 = kn0; k1 = kn1; k2 = kn2; k3 = kn3;
        v0 = vn0; v1 = vn1; v2 = vn2; v3 = vn3;
    }

    f32x4 oo[4] = {o0, o1, o2, o3};
#pragma unroll
    for (int j = 0; j < 4; j++)
#pragma unroll
        for (int r = 0; r < 4; r++) {
            int row = quad * 4 + r;
            xout[((size_t)(b * SS) + qt * 16 + row) * DD + h * 64 + j * 16 + l15] =
                f2bf(oo[j][r] * invC[r]);
        }

    __syncthreads();
    for (int i = t; i < 16 * 1024; i += 1024) {
        int row = i >> 10, col = i & 1023;
        attc[((size_t)b * SS + qt * 16 + row) * SS + col] = accc[row][col] + bc;
    }
}

extern "C" void kernel_launch(void* const* d_in, const int* in_sizes, int n_in,
                              void* d_out, int out_size, void* d_ws, size_t ws_size,
                              hipStream_t stream) {
    const float* query = (const float*)d_in[0];
    const float* key   = (const float*)d_in[1];
    const float* value = (const float*)d_in[2];
    const float* Wq = (const float*)d_in[3];
    const float* bq = (const float*)d_in[4];
    const float* Wk = (const float*)d_in[5];
    const float* bk = (const float*)d_in[6];
    const float* Wv = (const float*)d_in[7];
    const float* bv = (const float*)d_in[8];
    const float* Wo = (const float*)d_in[9];
    const float* bo = (const float*)d_in[10];
    const float* Wc = (const float*)d_in[11];
    const float* bc = (const float*)d_in[12];

    unsigned short* ws  = (unsigned short*)d_ws;
    unsigned short* xq  = ws;
    unsigned short* xk  = xq  + (size_t)4194304;
    unsigned short* xv  = xk  + (size_t)4194304;
    unsigned short* wtq = xv  + (size_t)4194304;
    unsigned short* wtk = wtq + (size_t)1048576;
    unsigned short* wtv = wtk + (size_t)1048576;
    unsigned short* wto = wtv + (size_t)1048576;
    unsigned short* qfb = wto + (size_t)1048576;    // Q frag-blocked (pre-scaled)
    unsigned short* kfb = qfb + (size_t)4194304;    // K frag-blocked
    unsigned short* vfb = kfb + (size_t)4194304;    // V frag-blocked
    unsigned short* xat = vfb + (size_t)4194304;    // [b,s,d]

    float* out0 = (float*)d_out;
    float* attc = out0 + (size_t)4194304;

    // fast-path extra workspace: Z only (256KB)
    const size_t base_bytes = 67108864;             // 32M ushorts above
    const size_t z_bytes = 262144;
    bool fast = ws_size >= base_bytes + z_bytes;

    hipLaunchKernelGGL(prep, dim3(8192), dim3(256), 0, stream,
                       query, key, value, xq, xk, xv,
                       Wq, Wk, Wv, Wo, wtq, wtk, wtv, wto);
    hipLaunchKernelGGL(gemm_qkv, dim3(768), dim3(256), 0, stream,
                       xq, xk, xv, wtq, wtk, wtv, bq, bk, bv, qfb, kfb, vfb);

    if (fast) {
        float* Zbuf = (float*)((char*)d_ws + base_bytes);
        hipLaunchKernelGGL(fattn_kernel, dim3(512), dim3(512), 0, stream,
                           qfb, kfb, vfb, Zbuf, xat);
        hipLaunchKernelGGL(tail_kernel, dim3(768), dim3(256), 0, stream,
                           qfb, kfb, Zbuf, Wc, bc, attc,
                           xat, wto, bo, out0);
    } else {
        hipLaunchKernelGGL(attn_kernel, dim3(256), dim3(1024), 0, stream,
                           qfb, kfb, vfb, Wc, bc, xat, attc);
        hipLaunchKernelGGL(gemm_o, dim3(256), dim3(256), 0, stream,
                           xat, wto, bo, out0);
    }
}